// Round 1
// baseline (1221.806 us; speedup 1.0000x reference)
//
#include <hip/hip_runtime.h>
#include <math.h>
#include <float.h>

#define B_  4
#define L_  1024
#define N_  16384
#define D_  256
#define K_  5
#define NCHUNK 8
#define CHUNK (N_/NCHUNK)   // 2048
#define TM 64               // L rows per block tile
#define TN 64               // N cols per tile
#define TK 64               // k chunk staged in LDS
#define PAD 68              // padded LDS row stride (floats), 16B-aligned rows

// ---------------- Phase A: inverse norms of memory rows ----------------
__global__ __launch_bounds__(256) void inv_norm_kernel(
    const float* __restrict__ mem, float* __restrict__ invn)
{
    int wave = (blockIdx.x * blockDim.x + threadIdx.x) >> 6;
    int lane = threadIdx.x & 63;
    if (wave >= B_ * N_) return;
    const float4* row = reinterpret_cast<const float4*>(mem + (size_t)wave * D_);
    float4 v = row[lane];                       // 64 lanes x 4 floats = 256
    float ss = v.x*v.x + v.y*v.y + v.z*v.z + v.w*v.w;
    #pragma unroll
    for (int off = 32; off > 0; off >>= 1)
        ss += __shfl_xor(ss, off, 64);
    if (lane == 0) {
        float n = sqrtf(ss);
        invn[wave] = 1.0f / fmaxf(n, 1e-12f);
    }
}

// ---------------- Phase B: scores + per-chunk top-5 ----------------
struct StageSM { float A[TM][PAD]; float Bt[TK][PAD]; };
struct MergeSM { float v[TM][16*K_]; int id[TM][16*K_]; };

__global__ __launch_bounds__(256) void score_topk_kernel(
    const float* __restrict__ enc, const float* __restrict__ mem,
    const float* __restrict__ invn,
    float* __restrict__ pval, int* __restrict__ pidx)
{
    __shared__ union { StageSM st; MergeSM mg; } sm;

    const int tid = threadIdx.x;
    const int ty = tid >> 4;          // 0..15 -> rows ty*4..+4
    const int tx = tid & 15;          // 0..15 -> cols tx*4..+4
    const int b  = blockIdx.z;
    const int l0 = blockIdx.y * TM;
    const int ch = blockIdx.x;
    const int n0 = ch * CHUNK;

    const float* __restrict__ encB  = enc + ((size_t)b * L_ + l0) * D_;
    const float* __restrict__ memB  = mem + (size_t)b * N_ * D_;
    const float* __restrict__ invnB = invn + (size_t)b * N_;

    // per-thread top-5 for 4 rows (static-indexed only)
    float tv[4][K_];
    int   tix[4][K_];
    #pragma unroll
    for (int i = 0; i < 4; ++i)
        #pragma unroll
        for (int p = 0; p < K_; ++p) { tv[i][p] = -FLT_MAX; tix[i][p] = 0; }

    // staging mapping: r = tid/4 (0..63), cq = tid%4; 4 passes cover 16 float4/row
    const int sr = tid >> 2;
    const int scq = tid & 3;

    for (int nt = 0; nt < CHUNK / TN; ++nt) {
        const int nbase = n0 + nt * TN;
        float acc[4][4];
        #pragma unroll
        for (int i = 0; i < 4; ++i)
            #pragma unroll
            for (int j = 0; j < 4; ++j) acc[i][j] = 0.0f;

        for (int kt = 0; kt < D_ / TK; ++kt) {
            const int k0 = kt * TK;
            __syncthreads();   // previous tile's reads done
            // stage A (enc) row-major [m][k]
            #pragma unroll
            for (int pass = 0; pass < 4; ++pass) {
                int c4 = scq + 4 * pass;   // 0..15
                float4 va = *reinterpret_cast<const float4*>(
                    &encB[(size_t)sr * D_ + k0 + 4 * c4]);
                *reinterpret_cast<float4*>(&sm.st.A[sr][4 * c4]) = va;
            }
            // stage Bt (mem) transposed [k][n]
            #pragma unroll
            for (int pass = 0; pass < 4; ++pass) {
                int c4 = scq + 4 * pass;
                float4 vb = *reinterpret_cast<const float4*>(
                    &memB[(size_t)(nbase + sr) * D_ + k0 + 4 * c4]);
                sm.st.Bt[4*c4 + 0][sr] = vb.x;
                sm.st.Bt[4*c4 + 1][sr] = vb.y;
                sm.st.Bt[4*c4 + 2][sr] = vb.z;
                sm.st.Bt[4*c4 + 3][sr] = vb.w;
            }
            __syncthreads();
            // inner: 16 k4-steps
            #pragma unroll
            for (int kk = 0; kk < TK / 4; ++kk) {
                const int k = kk * 4;
                float av[4][4], bv[4][4];
                #pragma unroll
                for (int i = 0; i < 4; ++i) {
                    float4 t = *reinterpret_cast<const float4*>(&sm.st.A[ty*4 + i][k]);
                    av[i][0] = t.x; av[i][1] = t.y; av[i][2] = t.z; av[i][3] = t.w;
                }
                #pragma unroll
                for (int q = 0; q < 4; ++q) {
                    float4 t = *reinterpret_cast<const float4*>(&sm.st.Bt[k + q][tx*4]);
                    bv[q][0] = t.x; bv[q][1] = t.y; bv[q][2] = t.z; bv[q][3] = t.w;
                }
                #pragma unroll
                for (int i = 0; i < 4; ++i)
                    #pragma unroll
                    for (int j = 0; j < 4; ++j)
                        #pragma unroll
                        for (int q = 0; q < 4; ++q)
                            acc[i][j] = fmaf(av[i][q], bv[q][j], acc[i][j]);
            }
        }

        // finished 256-k dots for this 64x64 tile -> scores + top-5 update
        float inv[4];
        #pragma unroll
        for (int j = 0; j < 4; ++j) inv[j] = invnB[nbase + tx*4 + j];

        #pragma unroll
        for (int i = 0; i < 4; ++i) {
            #pragma unroll
            for (int j = 0; j < 4; ++j) {
                float s = acc[i][j] * inv[j];
                int nidx = nbase + tx*4 + j;
                if (s > tv[i][K_-1]) {   // rare path
                    int pos = 0;
                    #pragma unroll
                    for (int p = 0; p < K_; ++p) pos += (tv[i][p] >= s) ? 1 : 0;
                    #pragma unroll
                    for (int p = K_-1; p >= 1; --p) {
                        if (p > pos) { tv[i][p] = tv[i][p-1]; tix[i][p] = tix[i][p-1]; }
                    }
                    #pragma unroll
                    for (int p = 0; p < K_; ++p)
                        if (p == pos) { tv[i][p] = s; tix[i][p] = nidx; }
                }
            }
        }
    }

    __syncthreads();   // staging arrays dead; union -> merge arrays
    #pragma unroll
    for (int i = 0; i < 4; ++i) {
        int row = ty*4 + i;
        #pragma unroll
        for (int p = 0; p < K_; ++p) {
            sm.mg.v [row][tx*K_ + p] = tv[i][p];
            sm.mg.id[row][tx*K_ + p] = tix[i][p];
        }
    }
    __syncthreads();

    if (tid < TM) {
        const int row = tid;
        float bvv[K_]; int bii[K_];
        #pragma unroll
        for (int p = 0; p < K_; ++p) { bvv[p] = -FLT_MAX; bii[p] = 0x7fffffff; }
        for (int c = 0; c < 16*K_; ++c) {
            float v = sm.mg.v[row][c];
            int   id = sm.mg.id[row][c];
            if (v > bvv[K_-1] || (v == bvv[K_-1] && id < bii[K_-1])) {
                int pos = 0;
                #pragma unroll
                for (int p = 0; p < K_; ++p)
                    pos += ((bvv[p] > v) || (bvv[p] == v && bii[p] < id)) ? 1 : 0;
                #pragma unroll
                for (int p = K_-1; p >= 1; --p)
                    if (p > pos) { bvv[p] = bvv[p-1]; bii[p] = bii[p-1]; }
                #pragma unroll
                for (int p = 0; p < K_; ++p)
                    if (p == pos) { bvv[p] = v; bii[p] = id; }
            }
        }
        size_t base = (((size_t)b * L_ + l0 + row) * NCHUNK + ch) * K_;
        #pragma unroll
        for (int p = 0; p < K_; ++p) { pval[base + p] = bvv[p]; pidx[base + p] = bii[p]; }
    }
}

// ---------------- Phase C: merge partials, gather, mean, linear ----------------
__global__ __launch_bounds__(256) void finalize_kernel(
    const float* __restrict__ enc, const float* __restrict__ mem,
    const float* __restrict__ W, const float* __restrict__ bias,
    const float* __restrict__ pval, const int* __restrict__ pidx,
    float* __restrict__ out)
{
    __shared__ float t_s[16][D_];
    __shared__ int idx_s[16][K_];

    const int blk = blockIdx.x;           // 0..255
    const int b = blk >> 6;               // 64 blocks per batch
    const int r0 = (blk & 63) << 4;       // 16 rows per block
    const int tid = threadIdx.x;

    if (tid < 16) {
        const int l = r0 + tid;
        float bvv[K_]; int bii[K_];
        #pragma unroll
        for (int p = 0; p < K_; ++p) { bvv[p] = -FLT_MAX; bii[p] = 0x7fffffff; }
        size_t base = ((size_t)b * L_ + l) * NCHUNK * K_;
        for (int c = 0; c < NCHUNK * K_; ++c) {
            float v = pval[base + c];
            int   id = pidx[base + c];
            int pos = 0;
            #pragma unroll
            for (int p = 0; p < K_; ++p)
                pos += ((bvv[p] > v) || (bvv[p] == v && bii[p] < id)) ? 1 : 0;
            if (pos < K_) {
                #pragma unroll
                for (int p = K_-1; p >= 1; --p)
                    if (p > pos) { bvv[p] = bvv[p-1]; bii[p] = bii[p-1]; }
                #pragma unroll
                for (int p = 0; p < K_; ++p)
                    if (p == pos) { bvv[p] = v; bii[p] = id; }
            }
        }
        #pragma unroll
        for (int p = 0; p < K_; ++p) idx_s[tid][p] = bii[p];
    }
    __syncthreads();

    // gather + mean + add encoded; thread = one d-column
    const int d = tid;
    #pragma unroll 1
    for (int r = 0; r < 16; ++r) {
        float acc = 0.0f;
        #pragma unroll
        for (int p = 0; p < K_; ++p)
            acc += mem[((size_t)b * N_ + idx_s[r][p]) * D_ + d];
        t_s[r][d] = acc * 0.2f + enc[((size_t)b * L_ + r0 + r) * D_ + d];
    }
    __syncthreads();

    // linear: out[l, dout] = sum_d t[l,d] * W[dout,d] + bias[dout]
    const int dout = tid;
    float accr[16];
    #pragma unroll
    for (int r = 0; r < 16; ++r) accr[r] = 0.0f;
    const float4* Wr = reinterpret_cast<const float4*>(W + (size_t)dout * D_);
    for (int d4 = 0; d4 < D_/4; ++d4) {
        float4 w = Wr[d4];
        #pragma unroll
        for (int r = 0; r < 16; ++r) {
            float4 t = *reinterpret_cast<const float4*>(&t_s[r][d4*4]);
            accr[r] = fmaf(w.x, t.x, accr[r]);
            accr[r] = fmaf(w.y, t.y, accr[r]);
            accr[r] = fmaf(w.z, t.z, accr[r]);
            accr[r] = fmaf(w.w, t.w, accr[r]);
        }
    }
    float bb = bias[dout];
    #pragma unroll
    for (int r = 0; r < 16; ++r)
        out[((size_t)b * L_ + r0 + r) * D_ + dout] = accr[r] + bb;
}

extern "C" void kernel_launch(void* const* d_in, const int* in_sizes, int n_in,
                              void* d_out, int out_size, void* d_ws, size_t ws_size,
                              hipStream_t stream)
{
    (void)in_sizes; (void)n_in; (void)out_size; (void)ws_size;
    const float* enc  = (const float*)d_in[0];
    const float* mem  = (const float*)d_in[1];
    const float* W    = (const float*)d_in[2];
    const float* bias = (const float*)d_in[3];
    float* out = (float*)d_out;

    // workspace carve-up
    char* ws = (char*)d_ws;
    float* invn = (float*)ws;                                   // B*N floats = 256 KB
    float* pval = (float*)(ws + (size_t)B_*N_*sizeof(float));   // B*L*NCHUNK*K = 640 KB
    int*   pidx = (int*)  (ws + (size_t)B_*N_*sizeof(float)
                              + (size_t)B_*L_*NCHUNK*K_*sizeof(float));

    // Phase A: inverse norms (4 rows per 256-thread block)
    {
        int rows = B_ * N_;
        int blocks = rows / 4;
        inv_norm_kernel<<<blocks, 256, 0, stream>>>(mem, invn);
    }
    // Phase B: tiled scores + chunked top-5
    {
        dim3 grid(NCHUNK, L_ / TM, B_);
        score_topk_kernel<<<grid, 256, 0, stream>>>(enc, mem, invn, pval, pidx);
    }
    // Phase C: merge + gather + mean + linear
    {
        finalize_kernel<<<B_ * L_ / 16, 256, 0, stream>>>(enc, mem, W, bias, pval, pidx, out);
    }
}

// Round 2
// 298.724 us; speedup vs baseline: 4.0901x; 4.0901x over previous
//
#include <hip/hip_runtime.h>
#include <math.h>
#include <float.h>

#define B_  4
#define L_  1024
#define N_  16384
#define D_  256
#define K_  5
#define NCH 16
#define CHUNK (N_/NCH)      // 1024
#define BM 128
#define BN 128
#define BK 64
#define TOPC 8              // per-chunk candidates kept
#define NCAND (NCH*TOPC)    // 128 candidates per row
#define RESC 16             // candidates rescored in fp32

typedef __attribute__((ext_vector_type(8))) short bf16x8;
typedef __attribute__((ext_vector_type(4))) float f32x4;

static __device__ __forceinline__ unsigned short f2bf(float f) {
    unsigned int u = __float_as_uint(f);
    unsigned int r = (u + 0x7FFFu + ((u >> 16) & 1u)) >> 16;
    return (unsigned short)r;
}
static __device__ __forceinline__ float bflo(unsigned int u) {   // low u16 -> float
    return __uint_as_float(u << 16);
}
static __device__ __forceinline__ float bfhi(unsigned int u) {   // high u16 -> float
    return __uint_as_float(u & 0xFFFF0000u);
}

// ---------------- Kernel 1: inv norms + bf16 copies ----------------
// rows [0, B*N): memory -> invn + memn_bf (= mem*invn, bf16)
// rows [B*N, B*N+B*L): encoded -> enc_bf (raw cast)
__global__ __launch_bounds__(256) void prep_kernel(
    const float* __restrict__ enc, const float* __restrict__ mem,
    float* __restrict__ invn, unsigned short* __restrict__ memn_bf,
    unsigned short* __restrict__ enc_bf)
{
    const int row = blockIdx.x * 4 + (threadIdx.x >> 6);
    const int lane = threadIdx.x & 63;
    if (row < B_ * N_) {
        float4 v = reinterpret_cast<const float4*>(mem + (size_t)row * D_)[lane];
        float ss = v.x*v.x + v.y*v.y + v.z*v.z + v.w*v.w;
        #pragma unroll
        for (int off = 32; off; off >>= 1) ss += __shfl_xor(ss, off, 64);
        float inv = 1.0f / fmaxf(sqrtf(ss), 1e-12f);
        if (lane == 0) invn[row] = inv;
        uint2 p;
        p.x = (unsigned)f2bf(v.x*inv) | ((unsigned)f2bf(v.y*inv) << 16);
        p.y = (unsigned)f2bf(v.z*inv) | ((unsigned)f2bf(v.w*inv) << 16);
        reinterpret_cast<uint2*>(memn_bf + (size_t)row * D_)[lane] = p;
    } else {
        int r2 = row - B_ * N_;
        if (r2 >= B_ * L_) return;
        float4 v = reinterpret_cast<const float4*>(enc + (size_t)r2 * D_)[lane];
        uint2 p;
        p.x = (unsigned)f2bf(v.x) | ((unsigned)f2bf(v.y) << 16);
        p.y = (unsigned)f2bf(v.z) | ((unsigned)f2bf(v.w) << 16);
        reinterpret_cast<uint2*>(enc_bf + (size_t)r2 * D_)[lane] = p;
    }
}

// ---------------- Kernel 2: bf16 MFMA screen + fused per-chunk top-8 ----------------
// grid (NCH, L/BM, B). Block 256 thr = 4 waves (2x2 over 128x128 tile).
__global__ __launch_bounds__(256, 2) void screen_kernel(
    const unsigned short* __restrict__ enc_bf,
    const unsigned short* __restrict__ memn_bf,
    float* __restrict__ pval, int* __restrict__ pidx)
{
    __shared__ __align__(16) unsigned char sA[BM * BK * 2];      // 16 KB
    __shared__ __align__(16) unsigned char sB[BN * BK * 2];      // 16 KB
    __shared__ __align__(16) unsigned char sS[128 * 272];        // scores bf16 [128][136] = 34 KB

    const int tid = threadIdx.x;
    const int lane = tid & 63;
    const int wv = tid >> 6;
    const int wm = wv >> 1, wn = wv & 1;
    const int b = blockIdx.z;
    const int l0 = blockIdx.y * BM;
    const int ch = blockIdx.x;

    // staging constants: thread handles quads f = i*256+tid -> row=f>>4, qc=f&15
    const int sqc = tid & 15;             // quad-col (4 bf16 = 8B)
    const int srow0 = tid >> 4;           // row base within group of 16
    const unsigned sswz = ((unsigned)(srow0 & 7)) << 4;
    const int swr_col = ((sqc * 8) ^ sswz);   // swizzled byte-in-row for ds_write

    // fragment read constants
    const int ra = wm * 64 + (lane & 15);
    const int rb = wn * 64 + (lane & 15);
    const unsigned aswz = ((unsigned)(ra & 7)) << 4;
    const unsigned bswz = ((unsigned)(rb & 7)) << 4;
    const int kgB = (lane >> 4) * 16;     // byte offset of lane's k-group

    const unsigned short* encB = enc_bf + ((size_t)b * L_ + l0) * D_;
    const unsigned short* memB = memn_bf + (size_t)b * N_ * D_;

    // per-(row,half) top-8 (row = tid>>1, half = tid&1)
    float tv[TOPC]; int ti[TOPC];
    #pragma unroll
    for (int p = 0; p < TOPC; ++p) { tv[p] = -FLT_MAX; ti[p] = 0; }
    const int scanrow = tid >> 1;
    const int half = tid & 1;

    for (int nt = 0; nt < CHUNK / BN; ++nt) {
        const int n0 = ch * CHUNK + nt * BN;
        f32x4 acc[4][4];
        #pragma unroll
        for (int i = 0; i < 4; ++i)
            #pragma unroll
            for (int j = 0; j < 4; ++j) acc[i][j] = (f32x4){0.f,0.f,0.f,0.f};

        for (int kt = 0; kt < D_ / BK; ++kt) {
            const int k0 = kt * BK;
            __syncthreads();
            // stage A and B: 8 quads each, coalesced 8B loads -> swizzled ds_write_b64
            #pragma unroll
            for (int i = 0; i < 8; ++i) {
                int row = i * 16 + srow0;
                uint2 va = *reinterpret_cast<const uint2*>(
                    &encB[(size_t)row * D_ + k0 + sqc * 4]);
                *reinterpret_cast<uint2*>(sA + row * 128 + swr_col) = va;
                uint2 vb = *reinterpret_cast<const uint2*>(
                    &memB[(size_t)(n0 + row) * D_ + k0 + sqc * 4]);
                *reinterpret_cast<uint2*>(sB + row * 128 + swr_col) = vb;
            }
            __syncthreads();
            #pragma unroll
            for (int kk = 0; kk < 2; ++kk) {
                const int kb = kk * 64 + kgB;
                bf16x8 af[4], bf[4];
                #pragma unroll
                for (int m = 0; m < 4; ++m)
                    af[m] = *reinterpret_cast<const bf16x8*>(
                        sA + (ra + m * 16) * 128 + (kb ^ aswz));
                #pragma unroll
                for (int n = 0; n < 4; ++n)
                    bf[n] = *reinterpret_cast<const bf16x8*>(
                        sB + (rb + n * 16) * 128 + (kb ^ bswz));
                #pragma unroll
                for (int m = 0; m < 4; ++m)
                    #pragma unroll
                    for (int n = 0; n < 4; ++n)
                        acc[m][n] = __builtin_amdgcn_mfma_f32_16x16x32_bf16(
                            af[m], bf[n], acc[m][n], 0, 0, 0);
            }
        }

        // epilogue: scores -> LDS bf16 [128][136]
        const int er0 = wm * 64 + (lane >> 4) * 4;
        const int ec0 = wn * 64 + (lane & 15);
        #pragma unroll
        for (int m = 0; m < 4; ++m)
            #pragma unroll
            for (int n = 0; n < 4; ++n) {
                int c = ec0 + n * 16;
                #pragma unroll
                for (int r = 0; r < 4; ++r) {
                    int rr = er0 + m * 16 + r;
                    *reinterpret_cast<unsigned short*>(sS + rr * 272 + c * 2) =
                        f2bf(acc[m][n][r]);
                }
            }
        __syncthreads();

        // scan: thread (row, half) scans 64 cols, maintains top-8
        const int cb = half * 64;
        #pragma unroll
        for (int j8 = 0; j8 < 8; ++j8) {
            uint4 w = *reinterpret_cast<const uint4*>(
                sS + scanrow * 272 + (cb + j8 * 8) * 2);
            int nb = n0 + cb + j8 * 8;
            float vs[8];
            vs[0]=bflo(w.x); vs[1]=bfhi(w.x); vs[2]=bflo(w.y); vs[3]=bfhi(w.y);
            vs[4]=bflo(w.z); vs[5]=bfhi(w.z); vs[6]=bflo(w.w); vs[7]=bfhi(w.w);
            #pragma unroll
            for (int e = 0; e < 8; ++e) {
                float v = vs[e];
                if (v > tv[TOPC-1]) {
                    int ci = nb + e;
                    bool ge[TOPC];
                    #pragma unroll
                    for (int p = 0; p < TOPC; ++p) ge[p] = (tv[p] >= v);
                    #pragma unroll
                    for (int p = TOPC-1; p >= 1; --p) {
                        tv[p] = ge[p] ? tv[p] : (ge[p-1] ? v : tv[p-1]);
                        ti[p] = ge[p] ? ti[p] : (ge[p-1] ? ci : ti[p-1]);
                    }
                    if (!ge[0]) { tv[0] = v; ti[0] = ci; }
                }
            }
        }
        __syncthreads();   // scan done before next epilogue overwrites sS
    }

    // merge halves: overlay merge arrays on sS
    float (*mgv)[TOPC] = reinterpret_cast<float (*)[TOPC]>(sS);
    int   (*mgi)[TOPC] = reinterpret_cast<int (*)[TOPC]>(sS + 256 * TOPC * 4);
    #pragma unroll
    for (int p = 0; p < TOPC; ++p) { mgv[tid][p] = tv[p]; mgi[tid][p] = ti[p]; }
    __syncthreads();
    if (tid < BM) {
        const int t0 = tid * 2;
        int i = 0, j = 0;
        size_t gb = (((size_t)b * L_ + l0 + tid) * NCH + ch) * TOPC;
        #pragma unroll
        for (int p = 0; p < TOPC; ++p) {
            float va = mgv[t0][i];   int ia = mgi[t0][i];
            float vb2 = mgv[t0+1][j]; int ib = mgi[t0+1][j];
            bool ta = (va > vb2) || (va == vb2 && ia < ib);
            pval[gb + p] = ta ? va : vb2;
            pidx[gb + p] = ta ? ia : ib;
            if (ta) ++i; else ++j;
        }
    }
}

// ---------------- Kernel 3: extract top-16, fp32 rescore, top-5, gather+mean ----------------
// one wave per row; block = 4 rows
__global__ __launch_bounds__(256) void rescore_kernel(
    const float* __restrict__ enc, const float* __restrict__ mem,
    const float* __restrict__ invn,
    const float* __restrict__ pval, const int* __restrict__ pidx,
    float* __restrict__ tbuf)
{
    __shared__ int cand_lds[4][RESC];
    const int wv = threadIdx.x >> 6;
    const int lane = threadIdx.x & 63;
    const int row = blockIdx.x * 4 + wv;       // 0..4095
    const int b = row >> 10;
    const int l = row & 1023;

    const size_t cb = (size_t)row * NCAND;
    float v0 = pval[cb + lane], v1 = pval[cb + 64 + lane];
    int i0 = pidx[cb + lane], i1 = pidx[cb + 64 + lane];

    #pragma unroll
    for (int rr = 0; rr < RESC; ++rr) {
        float mv; int mi;
        bool t0 = (v0 > v1) || (v0 == v1 && i0 < i1);
        mv = t0 ? v0 : v1; mi = t0 ? i0 : i1;
        #pragma unroll
        for (int off = 32; off; off >>= 1) {
            float ov = __shfl_xor(mv, off, 64);
            int oi = __shfl_xor(mi, off, 64);
            if (ov > mv || (ov == mv && oi < mi)) { mv = ov; mi = oi; }
        }
        if (lane == 0) cand_lds[wv][rr] = mi;
        if (i0 == mi) v0 = -FLT_MAX;
        if (i1 == mi) v1 = -FLT_MAX;
    }
    __syncthreads();

    // fp32 rescore: lane handles candidate lane>>2, quarter lane&3
    const int ci = cand_lds[wv][lane >> 2];
    const int q = lane & 3;
    const float4* er = reinterpret_cast<const float4*>(enc + ((size_t)b * L_ + l) * D_) + q * 16;
    const float4* mr = reinterpret_cast<const float4*>(mem + ((size_t)b * N_ + ci) * D_) + q * 16;
    float s = 0.0f;
    #pragma unroll
    for (int k = 0; k < 16; ++k) {
        float4 e = er[k], m = mr[k];
        s = fmaf(e.x, m.x, s); s = fmaf(e.y, m.y, s);
        s = fmaf(e.z, m.z, s); s = fmaf(e.w, m.w, s);
    }
    s += __shfl_xor(s, 1, 64);
    s += __shfl_xor(s, 2, 64);
    s *= invn[b * N_ + ci];

    // top-5 of the 16 rescored (dup lanes collapse via idx masking)
    float sw = s;
    int m0, m1, m2, m3, m4;
    #define PICK(MK) { \
        float mv = sw; int mi = ci; \
        if (sw == -FLT_MAX) mi = 0x7fffffff; \
        _Pragma("unroll") \
        for (int off = 32; off; off >>= 1) { \
            float ov = __shfl_xor(mv, off, 64); \
            int oi = __shfl_xor(mi, off, 64); \
            if (ov > mv || (ov == mv && oi < mi)) { mv = ov; mi = oi; } \
        } \
        MK = mi; \
        if (ci == mi) sw = -FLT_MAX; \
    }
    PICK(m0); PICK(m1); PICK(m2); PICK(m3); PICK(m4);
    #undef PICK

    // gather + mean + add encoded
    const float4* eb = reinterpret_cast<const float4*>(enc + ((size_t)b * L_ + l) * D_);
    const float4* mb = reinterpret_cast<const float4*>(mem + (size_t)b * N_ * D_);
    float4 e = eb[lane];
    float4 a0 = mb[(size_t)m0 * 64 + lane];
    float4 a1 = mb[(size_t)m1 * 64 + lane];
    float4 a2 = mb[(size_t)m2 * 64 + lane];
    float4 a3 = mb[(size_t)m3 * 64 + lane];
    float4 a4 = mb[(size_t)m4 * 64 + lane];
    float4 o;
    o.x = e.x + 0.2f * (a0.x + a1.x + a2.x + a3.x + a4.x);
    o.y = e.y + 0.2f * (a0.y + a1.y + a2.y + a3.y + a4.y);
    o.z = e.z + 0.2f * (a0.z + a1.z + a2.z + a3.z + a4.z);
    o.w = e.w + 0.2f * (a0.w + a1.w + a2.w + a3.w + a4.w);
    reinterpret_cast<float4*>(tbuf + (size_t)row * D_)[lane] = o;
}

// ---------------- Kernel 4: linear out = t @ W^T + b ----------------
__global__ __launch_bounds__(256) void linear_kernel(
    const float* __restrict__ tbuf, const float* __restrict__ W,
    const float* __restrict__ bias, float* __restrict__ out)
{
    __shared__ float t_s[16][D_];
    const int blk = blockIdx.x;
    const int b = blk >> 6;
    const int r0 = (blk & 63) << 4;
    const int tid = threadIdx.x;

    #pragma unroll
    for (int k = 0; k < 4; ++k) {
        int idx = k * 256 + tid;
        int row = idx >> 6, c4 = idx & 63;
        float4 v = reinterpret_cast<const float4*>(
            tbuf + ((size_t)b * L_ + r0 + row) * D_)[c4];
        *reinterpret_cast<float4*>(&t_s[row][c4 * 4]) = v;
    }
    __syncthreads();

    const int dout = tid;
    float accr[16];
    #pragma unroll
    for (int r = 0; r < 16; ++r) accr[r] = 0.0f;
    const float4* Wr = reinterpret_cast<const float4*>(W + (size_t)dout * D_);
    for (int d4 = 0; d4 < D_ / 4; ++d4) {
        float4 w = Wr[d4];
        #pragma unroll
        for (int r = 0; r < 16; ++r) {
            float4 t = *reinterpret_cast<const float4*>(&t_s[r][d4 * 4]);
            accr[r] = fmaf(w.x, t.x, accr[r]);
            accr[r] = fmaf(w.y, t.y, accr[r]);
            accr[r] = fmaf(w.z, t.z, accr[r]);
            accr[r] = fmaf(w.w, t.w, accr[r]);
        }
    }
    float bb = bias[dout];
    #pragma unroll
    for (int r = 0; r < 16; ++r)
        out[((size_t)b * L_ + r0 + r) * D_ + dout] = accr[r] + bb;
}

extern "C" void kernel_launch(void* const* d_in, const int* in_sizes, int n_in,
                              void* d_out, int out_size, void* d_ws, size_t ws_size,
                              hipStream_t stream)
{
    (void)in_sizes; (void)n_in; (void)out_size;
    const float* enc  = (const float*)d_in[0];
    const float* mem  = (const float*)d_in[1];
    const float* W    = (const float*)d_in[2];
    const float* bias = (const float*)d_in[3];
    float* out = (float*)d_out;

    // ws carve-up
    const size_t sz_memn = (size_t)B_ * N_ * D_ * 2;        // 33.5 MB
    const size_t sz_enc  = (size_t)B_ * L_ * D_ * 2;        // 2 MB
    const size_t sz_invn = (size_t)B_ * N_ * 4;             // 256 KB
    const size_t sz_pval = (size_t)B_ * L_ * NCAND * 4;     // 2 MB
    const size_t sz_pidx = sz_pval;                         // 2 MB
    const size_t sz_tbuf = (size_t)B_ * L_ * D_ * 4;        // 4 MB
    const size_t need = sz_memn + sz_enc + sz_invn + sz_pval + sz_pidx + sz_tbuf;
    if (ws_size < need) return;   // ws too small: leave output poisoned (diagnosable)

    char* p = (char*)d_ws;
    unsigned short* memn_bf = (unsigned short*)p;  p += sz_memn;
    unsigned short* enc_bf  = (unsigned short*)p;  p += sz_enc;
    float* invn = (float*)p;  p += sz_invn;
    float* pval = (float*)p;  p += sz_pval;
    int*   pidx = (int*)p;    p += sz_pidx;
    float* tbuf = (float*)p;

    {   // prep: one wave per row, 4 waves/block
        int rows = B_ * N_ + B_ * L_;
        prep_kernel<<<(rows + 3) / 4, 256, 0, stream>>>(enc, mem, invn, memn_bf, enc_bf);
    }
    {   // screen
        dim3 grid(NCH, L_ / BM, B_);
        screen_kernel<<<grid, 256, 0, stream>>>(enc_bf, memn_bf, pval, pidx);
    }
    {   // rescore
        rescore_kernel<<<(B_ * L_) / 4, 256, 0, stream>>>(enc, mem, invn, pval, pidx, tbuf);
    }
    {   // linear
        linear_kernel<<<B_ * L_ / 16, 256, 0, stream>>>(tbuf, W, bias, out);
    }
}